// Round 11
// baseline (275.243 us; speedup 1.0000x reference)
//
#include <hip/hip_runtime.h>
#include <hip/hip_cooperative_groups.h>
#include <hip/hip_bf16.h>

namespace cg = cooperative_groups;

typedef __attribute__((ext_vector_type(8))) short short8;
typedef __attribute__((ext_vector_type(4))) float f32x4;

#define NTOK 4096
#define DIN  1024
#define DOUT 1024
#define KTOT 1152   // 1024 (W) + 128 (LoRA)
#define XLD  1152
#define TLDS 200    // Tsm leading dim (f32)

__device__ __forceinline__ unsigned short f2bf(float f) {
    __hip_bfloat16 h = __float2bfloat16(f);
    return __builtin_bit_cast(unsigned short, h);
}

__device__ __forceinline__ void gload16(const void* g, void* l) {
    __builtin_amdgcn_global_load_lds((const __attribute__((address_space(1))) void*)g,
                                     (__attribute__((address_space(3))) void*)l, 16, 0, 0);
}

__device__ __forceinline__ uint4 pack2(float4 v0, float4 v1) {
    union { unsigned short u[8]; uint4 q; } pk;
    pk.u[0] = f2bf(v0.x); pk.u[1] = f2bf(v0.y); pk.u[2] = f2bf(v0.z); pk.u[3] = f2bf(v0.w);
    pk.u[4] = f2bf(v1.x); pk.u[5] = f2bf(v1.y); pk.u[6] = f2bf(v1.z); pk.u[7] = f2bf(v1.w);
    return pk.q;
}

__device__ __forceinline__ uint4 pack8(const float* s) {
    return pack2(*(const float4*)s, *(const float4*)(s + 4));
}

// ======================= single cooperative kernel ==========================
// grid 512 x 256. Phase0: weight prep. Phase1 (blocks<256): gemm1+softmax+coef.
// Phase2 (all): gemm2. grid.sync() between phases.
__global__ __launch_bounds__(256) void k_fused(const float* __restrict__ x,
                                               const float* __restrict__ w,
                                               const float* __restrict__ gate_w,
                                               const float* __restrict__ lora_U,
                                               const float* __restrict__ lora_V,
                                               __hip_bfloat16* __restrict__ Xcat,
                                               __hip_bfloat16* __restrict__ Ucat,
                                               __hip_bfloat16* __restrict__ Wcat,
                                               float* __restrict__ out) {
    __shared__ char smem[53248];
    cg::grid_group grid = cg::this_grid();
    const int bid = blockIdx.x;
    const int t = threadIdx.x, lane = t & 63, wid = t >> 6;
    const int l7 = lane & 7, l8 = lane >> 3, l15 = lane & 15, l16 = lane >> 4;
    const int scol = ((l7 ^ l8) << 3);             // pre-swizzled global col
    int sw[2];
#pragma unroll
    for (int ks = 0; ks < 2; ++ks) sw[ks] = (((ks * 4 + l16) ^ l7) << 4);

    // ---------------- Phase 0: Ucat = [lora_U;gate_w;0], Wcat = [W|V2] ------
    for (int u = bid; u < 672; u += 512) {
        if (u < 96) {
            int idx = u * 256 + t;                 // 192 rows x 128 groups
            int r = idx >> 7, g = idx & 127;
            uint4 q = make_uint4(0u, 0u, 0u, 0u);
            if (r < 128)      q = pack8(lora_U + (size_t)r * DIN + g * 8);
            else if (r < 136) q = pack8(gate_w + (size_t)(r - 128) * DIN + g * 8);
            *(uint4*)(Ucat + (size_t)r * DIN + g * 8) = q;
        } else {
            int idx = (u - 96) * 256 + t;          // 1024 rows x 144 groups
            int o = idx / 144, g = idx - o * 144;
            const float* s;
            if (g < 128) s = w + (size_t)o * DIN + g * 8;
            else {
                int i0 = (g - 128) * 8;
                int e = i0 >> 4, r = i0 & 15;
                s = lora_V + (size_t)e * (DOUT * 16) + (size_t)o * 16 + r;
            }
            *(uint4*)(Wcat + (size_t)o * KTOT + g * 8) = pack8(s);
        }
    }
    __threadfence();
    grid.sync();

    // ---------------- Phase 1 (blocks < 256): gemm1f ------------------------
    if (bid < 256) {
        float (*Tsm)[TLDS] = (float(*)[TLDS])smem;
        const int row0 = bid * 16;

        f32x4 acc[3];
#pragma unroll
        for (int n = 0; n < 3; ++n) acc[n] = (f32x4){0.f, 0.f, 0.f, 0.f};

        const int ar = (t & 127) >> 3;             // A-staging row 0..15
        const int ac8 = (t & 7) * 8;
        const int abyte = ar * 128 + (((t & 7) ^ (ar & 7)) << 4);

        int boff[3];
#pragma unroll
        for (int n = 0; n < 3; ++n) boff[n] = (wid * 48 + n * 16 + l15) * 128;
        const int aoff = l15 * 128;

        // prologue: stage kt=0 into buf0
        if (t < 128) {
            uint4 q = pack8(x + (size_t)(row0 + ar) * DIN + 0 + ac8);
            *(uint4*)(smem + 0 * 2048 + abyte) = q;
            *(uint4*)(Xcat + (size_t)(row0 + ar) * XLD + 0 + ac8) = q;
        }
#pragma unroll
        for (int i = 0; i < 6; ++i) {
            int cj = wid * 6 + i;
            gload16(Ucat + (size_t)(cj * 8 + l8) * DIN + 0 + scol,
                    smem + 4096 + cj * 1024);
        }
        __syncthreads();

        int cur = 0;
        for (int kt = 0; kt < 16; ++kt) {
            const bool hasNext = kt < 15;
            const int k1 = (kt + 1) << 6;
            float4 f0, f1;
            if (hasNext && t < 128) {              // issue x loads early
                const float* s = x + (size_t)(row0 + ar) * DIN + k1 + ac8;
                f0 = *(const float4*)s; f1 = *(const float4*)(s + 4);
            }
            if (hasNext) {                         // prefetch B for kt+1
#pragma unroll
                for (int i = 0; i < 6; ++i) {
                    int cj = wid * 6 + i;
                    gload16(Ucat + (size_t)(cj * 8 + l8) * DIN + k1 + scol,
                            smem + 4096 + (cur ^ 1) * 24576 + cj * 1024);
                }
            }
            const char* Ab = smem + cur * 2048;
            const char* Bb = smem + 4096 + cur * 24576;
#pragma unroll
            for (int ks = 0; ks < 2; ++ks) {
                short8 af = *(const short8*)(Ab + aoff + sw[ks]);
#pragma unroll
                for (int n = 0; n < 3; ++n) {
                    short8 bf = *(const short8*)(Bb + boff[n] + sw[ks]);
                    acc[n] = __builtin_amdgcn_mfma_f32_16x16x32_bf16(af, bf, acc[n], 0, 0, 0);
                }
            }
            if (hasNext && t < 128) {              // convert + ds_write late
                uint4 q = pack2(f0, f1);
                *(uint4*)(smem + (cur ^ 1) * 2048 + abyte) = q;
                *(uint4*)(Xcat + (size_t)(row0 + ar) * XLD + k1 + ac8) = q;
            }
            __syncthreads();
            cur ^= 1;
        }

        // acc -> Tsm (f32), C/D mapping col=lane&15, row=(lane>>4)*4+j
#pragma unroll
        for (int n = 0; n < 3; ++n)
#pragma unroll
            for (int j = 0; j < 4; ++j)
                Tsm[l16 * 4 + j][wid * 48 + n * 16 + l15] = acc[n][j];
        __syncthreads();

        // softmax + coef: 8 threads per token
        if (t < 128) {
            const int tok = t >> 3, e = t & 7;
            float l[8];
#pragma unroll
            for (int i = 0; i < 8; ++i) l[i] = Tsm[tok][128 + i];
            float m = l[0];
#pragma unroll
            for (int i = 1; i < 8; ++i) m = fmaxf(m, l[i]);
            float s = 0.f;
#pragma unroll
            for (int i = 0; i < 8; ++i) s += __expf(l[i] - m);
            const float g = __expf(l[e] - m) / s * 0.0625f;   // gate * 1/R
            union { unsigned short u[16]; uint4 q[2]; } pk;
#pragma unroll
            for (int jj = 0; jj < 16; ++jj) pk.u[jj] = f2bf(g * Tsm[tok][e * 16 + jj]);
            uint4* dst = (uint4*)(Xcat + (size_t)(row0 + tok) * XLD + 1024 + e * 16);
            dst[0] = pk.q[0]; dst[1] = pk.q[1];
        }
    }
    __threadfence();
    grid.sync();

    // ---------------- Phase 2 (all 512 blocks): gemm2 -----------------------
    {
        const int xcd = bid & 7, j = bid >> 3;
        const int bx = xcd * 4 + (j & 3), by = j >> 2;
        const int row0 = bx * 128, col0 = by * 64;
        const int wr = wid >> 1, wc = wid & 1;

        f32x4 zf = {0.f, 0.f, 0.f, 0.f};
        f32x4 acc[4][2];
#pragma unroll
        for (int m = 0; m < 4; ++m)
#pragma unroll
            for (int n = 0; n < 2; ++n) acc[m][n] = zf;

        int aoff[4], boff[2];
#pragma unroll
        for (int m = 0; m < 4; ++m) aoff[m] = (wr * 64 + m * 16 + l15) * 128;
#pragma unroll
        for (int n = 0; n < 2; ++n) boff[n] = (wc * 32 + n * 16 + l15) * 128;

#define G2_STAGE(buf, kt)                                                      \
    {                                                                          \
        const int k0_ = (kt) << 6;                                             \
        _Pragma("unroll")                                                      \
        for (int i = 0; i < 4; ++i) {                                          \
            int ci = wid * 4 + i;                                              \
            gload16(Xcat + (size_t)(row0 + ci * 8 + l8) * XLD + k0_ + scol,    \
                    smem + (buf) * 16384 + ci * 1024);                         \
        }                                                                      \
        _Pragma("unroll")                                                      \
        for (int i = 0; i < 2; ++i) {                                          \
            int cj = wid * 2 + i;                                              \
            gload16(Wcat + (size_t)(col0 + cj * 8 + l8) * KTOT + k0_ + scol,   \
                    smem + 32768 + (buf) * 8192 + cj * 1024);                  \
        }                                                                      \
    }

#define G2_COMP(buf)                                                           \
    {                                                                          \
        const char* Ab = smem + (buf) * 16384;                                 \
        const char* Bb = smem + 32768 + (buf) * 8192;                          \
        _Pragma("unroll")                                                      \
        for (int ks = 0; ks < 2; ++ks) {                                       \
            short8 af[4], bf[2];                                               \
            _Pragma("unroll")                                                  \
            for (int m = 0; m < 4; ++m)                                        \
                af[m] = *(const short8*)(Ab + aoff[m] + sw[ks]);               \
            _Pragma("unroll")                                                  \
            for (int n = 0; n < 2; ++n)                                        \
                bf[n] = *(const short8*)(Bb + boff[n] + sw[ks]);               \
            _Pragma("unroll")                                                  \
            for (int m = 0; m < 4; ++m)                                        \
                _Pragma("unroll")                                              \
                for (int n = 0; n < 2; ++n)                                    \
                    acc[m][n] = __builtin_amdgcn_mfma_f32_16x16x32_bf16(       \
                        af[m], bf[n], acc[m][n], 0, 0, 0);                     \
        }                                                                      \
    }

        G2_STAGE(0, 0);
        __syncthreads();
        int cur = 0;
        for (int kt = 0; kt < 17; ++kt) {
            G2_STAGE(cur ^ 1, kt + 1);     // prefetch next K-tile
            G2_COMP(cur);                  // compute current
            __syncthreads();
            cur ^= 1;
        }
        G2_COMP(cur);                      // epilogue K-tile 17

#pragma unroll
        for (int m = 0; m < 4; ++m)
#pragma unroll
            for (int n = 0; n < 2; ++n)
#pragma unroll
                for (int jj = 0; jj < 4; ++jj)
                    out[(size_t)(row0 + wr * 64 + m * 16 + l16 * 4 + jj) * DOUT
                        + col0 + wc * 32 + n * 16 + l15] = acc[m][n][jj];
#undef G2_STAGE
#undef G2_COMP
    }
}

extern "C" void kernel_launch(void* const* d_in, const int* in_sizes, int n_in,
                              void* d_out, int out_size, void* d_ws, size_t ws_size,
                              hipStream_t stream) {
    const float* x      = (const float*)d_in[0];   // (4,1024,1024)
    const float* weight = (const float*)d_in[1];   // (1024,1024)
    const float* gate_w = (const float*)d_in[2];   // (8,1024)
    const float* lora_U = (const float*)d_in[3];   // (8,16,1024)
    const float* lora_V = (const float*)d_in[4];   // (8,1024,16)
    float* out = (float*)d_out;

    char* ws = (char*)d_ws;
    __hip_bfloat16* Xcat = (__hip_bfloat16*)ws;                        // 4096x1152 (9.44 MB)
    __hip_bfloat16* Ucat = (__hip_bfloat16*)(ws + 9437184);            // 192x1024  (0.39 MB)
    __hip_bfloat16* Wcat = (__hip_bfloat16*)(ws + 9437184 + 393216);   // 1024x1152 (2.36 MB)

    void* args[] = {(void*)&x, (void*)&weight, (void*)&gate_w, (void*)&lora_U,
                    (void*)&lora_V, (void*)&Xcat, (void*)&Ucat, (void*)&Wcat,
                    (void*)&out};
    hipLaunchCooperativeKernel((void*)k_fused, dim3(512), dim3(256), args, 0, stream);
}

// Round 12
// 42.195 us; speedup vs baseline: 6.5232x; 6.5232x over previous
//
#include <hip/hip_runtime.h>
#include <hip/hip_bf16.h>

typedef __attribute__((ext_vector_type(8))) short short8;
typedef __attribute__((ext_vector_type(4))) float f32x4;

#define NTOK 4096
#define DIN  1024
#define DOUT 1024
#define KTOT 1152   // 1024 (W) + 128 (LoRA)
#define XLD  1152
#define TLDS 200    // Tsm leading dim (f32)

__device__ __forceinline__ unsigned short f2bf(float f) {
    __hip_bfloat16 h = __float2bfloat16(f);
    return __builtin_bit_cast(unsigned short, h);
}

__device__ __forceinline__ void gload16(const void* g, void* l) {
    __builtin_amdgcn_global_load_lds((const __attribute__((address_space(1))) void*)g,
                                     (__attribute__((address_space(3))) void*)l, 16, 0, 0);
}

__device__ __forceinline__ uint4 pack2(float4 v0, float4 v1) {
    union { unsigned short u[8]; uint4 q; } pk;
    pk.u[0] = f2bf(v0.x); pk.u[1] = f2bf(v0.y); pk.u[2] = f2bf(v0.z); pk.u[3] = f2bf(v0.w);
    pk.u[4] = f2bf(v1.x); pk.u[5] = f2bf(v1.y); pk.u[6] = f2bf(v1.z); pk.u[7] = f2bf(v1.w);
    return pk.q;
}

__device__ __forceinline__ uint4 pack8(const float* s) {
    return pack2(*(const float4*)s, *(const float4*)(s + 4));
}

// ---- weight prep: Ucat (192x1024) = [lora_U;gate_w;0], Wcat (1024x1152) = [W|V2]
__global__ __launch_bounds__(256) void k_cvtuw(const float* __restrict__ lora_U,
                                               const float* __restrict__ gate_w,
                                               const float* __restrict__ w,
                                               const float* __restrict__ lora_V,
                                               __hip_bfloat16* __restrict__ Ucat,
                                               __hip_bfloat16* __restrict__ Wcat) {
    int b = blockIdx.x;
    if (b < 96) {
        int idx = b * 256 + threadIdx.x;          // 192 rows x 128 groups
        int r = idx >> 7, g = idx & 127;
        uint4 q = make_uint4(0u, 0u, 0u, 0u);
        if (r < 128)      q = pack8(lora_U + (size_t)r * DIN + g * 8);
        else if (r < 136) q = pack8(gate_w + (size_t)(r - 128) * DIN + g * 8);
        *(uint4*)(Ucat + (size_t)r * DIN + g * 8) = q;
    } else {
        int idx = (b - 96) * 256 + threadIdx.x;   // 1024 rows x 144 groups
        int o = idx / 144, g = idx - o * 144;
        const float* s;
        if (g < 128) s = w + (size_t)o * DIN + g * 8;
        else {
            int i0 = (g - 128) * 8;               // 0..127 in LoRA cols
            int e = i0 >> 4, r = i0 & 15;         // r in {0,8}
            s = lora_V + (size_t)e * (DOUT * 16) + (size_t)o * 16 + r;
        }
        *(uint4*)(Wcat + (size_t)o * KTOT + g * 8) = pack8(s);
    }
}

// ---- GEMM1 fused: T = x @ Ucat^T (K=1024), softmax gate, coef -> Xcat ------
// BM=16, BN=192, BK=64, 256 threads = 4 waves, wave tile 16x48, grid 256.
// 2-phase prefetch: double-buffered LDS, STAGE(kt+1) issued before compute(kt).
__global__ __launch_bounds__(256) void k_gemm1f(const float* __restrict__ x,
                                                const __hip_bfloat16* __restrict__ Ucat,
                                                __hip_bfloat16* __restrict__ Xcat) {
    __shared__ char smem[53248];                   // A: 2x2KB @0; B: 2x24KB @4096
    float (*Tsm)[TLDS] = (float(*)[TLDS])smem;     // 12.8KB reuse after loop

    const int t = threadIdx.x, lane = t & 63, wid = t >> 6;
    const int row0 = blockIdx.x * 16;
    const int l7 = lane & 7, l8 = lane >> 3, l15 = lane & 15, l16 = lane >> 4;
    const int scol = ((l7 ^ l8) << 3);             // pre-swizzled global col (B)

    f32x4 acc[3];
#pragma unroll
    for (int n = 0; n < 3; ++n) acc[n] = (f32x4){0.f, 0.f, 0.f, 0.f};

    const int ar = (t & 127) >> 3;                 // A-staging row 0..15
    const int ac8 = (t & 7) * 8;                   // A-staging col group
    const int abyte = ar * 128 + (((t & 7) ^ (ar & 7)) << 4);   // swizzled LDS slot

    int boff[3];
#pragma unroll
    for (int n = 0; n < 3; ++n) boff[n] = (wid * 48 + n * 16 + l15) * 128;
    const int aoff = l15 * 128;
    int sw[2];
#pragma unroll
    for (int ks = 0; ks < 2; ++ks) sw[ks] = (((ks * 4 + l16) ^ l7) << 4);

    // prologue: stage kt=0 into buf0
    if (t < 128) {
        uint4 q = pack8(x + (size_t)(row0 + ar) * DIN + 0 + ac8);
        *(uint4*)(smem + 0 * 2048 + abyte) = q;
        *(uint4*)(Xcat + (size_t)(row0 + ar) * XLD + 0 + ac8) = q;
    }
#pragma unroll
    for (int i = 0; i < 6; ++i) {
        int cj = wid * 6 + i;
        gload16(Ucat + (size_t)(cj * 8 + l8) * DIN + 0 + scol,
                smem + 4096 + cj * 1024);
    }
    __syncthreads();

    int cur = 0;
    for (int kt = 0; kt < 16; ++kt) {
        const bool hasNext = kt < 15;
        const int k1 = (kt + 1) << 6;
        float4 f0, f1;
        if (hasNext && t < 128) {                  // issue x loads early
            const float* s = x + (size_t)(row0 + ar) * DIN + k1 + ac8;
            f0 = *(const float4*)s; f1 = *(const float4*)(s + 4);
        }
        if (hasNext) {                             // prefetch B for kt+1
#pragma unroll
            for (int i = 0; i < 6; ++i) {
                int cj = wid * 6 + i;
                gload16(Ucat + (size_t)(cj * 8 + l8) * DIN + k1 + scol,
                        smem + 4096 + (cur ^ 1) * 24576 + cj * 1024);
            }
        }
        // compute from buf[cur]
        const char* Ab = smem + cur * 2048;
        const char* Bb = smem + 4096 + cur * 24576;
#pragma unroll
        for (int ks = 0; ks < 2; ++ks) {
            short8 af = *(const short8*)(Ab + aoff + sw[ks]);
#pragma unroll
            for (int n = 0; n < 3; ++n) {
                short8 bf = *(const short8*)(Bb + boff[n] + sw[ks]);
                acc[n] = __builtin_amdgcn_mfma_f32_16x16x32_bf16(af, bf, acc[n], 0, 0, 0);
            }
        }
        if (hasNext && t < 128) {                  // convert + ds_write late
            uint4 q = pack2(f0, f1);
            *(uint4*)(smem + (cur ^ 1) * 2048 + abyte) = q;
            *(uint4*)(Xcat + (size_t)(row0 + ar) * XLD + k1 + ac8) = q;
        }
        __syncthreads();
        cur ^= 1;
    }

    // acc -> Tsm (f32), C/D mapping col=lane&15, row=(lane>>4)*4+j
#pragma unroll
    for (int n = 0; n < 3; ++n)
#pragma unroll
        for (int j = 0; j < 4; ++j)
            Tsm[l16 * 4 + j][wid * 48 + n * 16 + l15] = acc[n][j];
    __syncthreads();

    // softmax + coef: 8 threads per token (16 tokens x 8 experts)
    if (t < 128) {
        const int tok = t >> 3, e = t & 7;
        float l[8];
#pragma unroll
        for (int i = 0; i < 8; ++i) l[i] = Tsm[tok][128 + i];
        float m = l[0];
#pragma unroll
        for (int i = 1; i < 8; ++i) m = fmaxf(m, l[i]);
        float s = 0.f;
#pragma unroll
        for (int i = 0; i < 8; ++i) s += __expf(l[i] - m);
        const float g = __expf(l[e] - m) / s * 0.0625f;   // gate * 1/R
        union { unsigned short u[16]; uint4 q[2]; } pk;
#pragma unroll
        for (int jj = 0; jj < 16; ++jj) pk.u[jj] = f2bf(g * Tsm[tok][e * 16 + jj]);
        uint4* dst = (uint4*)(Xcat + (size_t)(row0 + tok) * XLD + 1024 + e * 16);
        dst[0] = pk.q[0]; dst[1] = pk.q[1];
    }
}

// ---- GEMM2: out = Xcat @ Wcat^T (K=1152) -----------------------------------
// BM=BN=128, BK=64, 512 threads = 8 waves (2x4), wave tile 64x32.
// 2-phase prefetch dbuf (64KB LDS). Grid 256 = 1 block/CU (all CUs busy).
// XCD-bijective swizzle: xcd=b&7 owns row-tiles xcd*4..+3 x 8 col-tiles
// (per-XCD L2 set: A-slice 1.2MB + Wcat 2.4MB < 4MB).
__global__ __launch_bounds__(512) void k_gemm2(const __hip_bfloat16* __restrict__ A,
                                               const __hip_bfloat16* __restrict__ B,
                                               float* __restrict__ out) {
    __shared__ char smem[65536];                   // A: 2x16KB @0; B: 2x16KB @32768
    const int b = blockIdx.x;
    const int xcd = b & 7, j = b >> 3;             // j in 0..31
    const int bx = xcd * 4 + (j & 3), by = j >> 2; // bx 0..31, by 0..7
    const int row0 = bx * 128, col0 = by * 128;

    const int t = threadIdx.x, lane = t & 63, wid = t >> 6;
    const int wr = wid >> 2, wc = wid & 3;         // 2x4 wave grid
    const int l7 = lane & 7, l8 = lane >> 3, l15 = lane & 15, l16 = lane >> 4;
    const int scol = ((l7 ^ l8) << 3);

    f32x4 zf = {0.f, 0.f, 0.f, 0.f};
    f32x4 acc[4][2];
#pragma unroll
    for (int m = 0; m < 4; ++m)
#pragma unroll
        for (int n = 0; n < 2; ++n) acc[m][n] = zf;

    int aoff[4], boff[2], sw[2];
#pragma unroll
    for (int m = 0; m < 4; ++m) aoff[m] = (wr * 64 + m * 16 + l15) * 128;
#pragma unroll
    for (int n = 0; n < 2; ++n) boff[n] = (wc * 32 + n * 16 + l15) * 128;
#pragma unroll
    for (int ks = 0; ks < 2; ++ks) sw[ks] = (((ks * 4 + l16) ^ l7) << 4);

#define G2_STAGE(buf, kt)                                                      \
    {                                                                          \
        const int k0_ = (kt) << 6;                                             \
        _Pragma("unroll")                                                      \
        for (int i = 0; i < 2; ++i) {                                          \
            int ci = wid * 2 + i;              /* 16 chunks x 8 rows = 128 */  \
            gload16(A + (size_t)(row0 + ci * 8 + l8) * XLD + k0_ + scol,       \
                    smem + (buf) * 16384 + ci * 1024);                         \
            gload16(B + (size_t)(col0 + ci * 8 + l8) * KTOT + k0_ + scol,      \
                    smem + 32768 + (buf) * 16384 + ci * 1024);                 \
        }                                                                      \
    }

#define G2_COMP(buf)                                                           \
    {                                                                          \
        const char* Ab = smem + (buf) * 16384;                                 \
        const char* Bb = smem + 32768 + (buf) * 16384;                         \
        _Pragma("unroll")                                                      \
        for (int ks = 0; ks < 2; ++ks) {                                       \
            short8 af[4], bf[2];                                               \
            _Pragma("unroll")                                                  \
            for (int m = 0; m < 4; ++m)                                        \
                af[m] = *(const short8*)(Ab + aoff[m] + sw[ks]);               \
            _Pragma("unroll")                                                  \
            for (int n = 0; n < 2; ++n)                                        \
                bf[n] = *(const short8*)(Bb + boff[n] + sw[ks]);               \
            _Pragma("unroll")                                                  \
            for (int m = 0; m < 4; ++m)                                        \
                _Pragma("unroll")                                              \
                for (int n = 0; n < 2; ++n)                                    \
                    acc[m][n] = __builtin_amdgcn_mfma_f32_16x16x32_bf16(       \
                        af[m], bf[n], acc[m][n], 0, 0, 0);                     \
        }                                                                      \
    }

    G2_STAGE(0, 0);
    __syncthreads();
    int cur = 0;
    for (int kt = 0; kt < 17; ++kt) {
        G2_STAGE(cur ^ 1, kt + 1);     // prefetch next K-tile
        G2_COMP(cur);                  // compute current (loads fly underneath)
        __syncthreads();
        cur ^= 1;
    }
    G2_COMP(cur);                      // epilogue K-tile 17

#pragma unroll
    for (int m = 0; m < 4; ++m)
#pragma unroll
        for (int n = 0; n < 2; ++n)
#pragma unroll
            for (int jj = 0; jj < 4; ++jj)
                out[(size_t)(row0 + wr * 64 + m * 16 + l16 * 4 + jj) * DOUT
                    + col0 + wc * 32 + n * 16 + l15] = acc[m][n][jj];
#undef G2_STAGE
#undef G2_COMP
}

extern "C" void kernel_launch(void* const* d_in, const int* in_sizes, int n_in,
                              void* d_out, int out_size, void* d_ws, size_t ws_size,
                              hipStream_t stream) {
    const float* x      = (const float*)d_in[0];   // (4,1024,1024)
    const float* weight = (const float*)d_in[1];   // (1024,1024)
    const float* gate_w = (const float*)d_in[2];   // (8,1024)
    const float* lora_U = (const float*)d_in[3];   // (8,16,1024)
    const float* lora_V = (const float*)d_in[4];   // (8,1024,16)
    float* out = (float*)d_out;

    char* ws = (char*)d_ws;
    __hip_bfloat16* Xcat = (__hip_bfloat16*)ws;                        // 4096x1152 (9.44 MB)
    __hip_bfloat16* Ucat = (__hip_bfloat16*)(ws + 9437184);            // 192x1024  (0.39 MB)
    __hip_bfloat16* Wcat = (__hip_bfloat16*)(ws + 9437184 + 393216);   // 1024x1152 (2.36 MB)

    k_cvtuw<<<672, 256, 0, stream>>>(lora_U, gate_w, weight, lora_V, Ucat, Wcat);
    k_gemm1f<<<256, 256, 0, stream>>>(x, Ucat, Xcat);
    k_gemm2<<<256, 512, 0, stream>>>(Xcat, Wcat, out);
}